// Round 6
// baseline (7528.371 us; speedup 1.0000x reference)
//
#include <hip/hip_runtime.h>
#include <hip/hip_bf16.h>

// ---------------------------------------------------------------------------
// PointNet++ encoder (4 SA stages) for MI355X.
// Stage pipeline: FPS -> gather new_xyz -> ball query -> fused group+MLP+maxpool.
// FPS / ball-query distance math matches numpy per-op IEEE semantics exactly
// (argmax selection must be exact; xyz output is raw copies).
// Stage-1 FPS is bucketed: spatial sort + per-chunk conservative skip bounds
// (skips are provably exact under fp32 error margins), so selected indices are
// bit-identical to the brute-force scan.
// ---------------------------------------------------------------------------

#define B_SZ 4

typedef float v2f __attribute__((ext_vector_type(2)));
typedef unsigned long long u64;

// Packed-FP32 helpers (VOP3P). Each half is a plain IEEE f32 op, so results
// are bitwise identical to scalar v_add_f32/v_mul_f32.
__device__ __forceinline__ v2f pk_add(v2f a, v2f b) {
  v2f d;
  asm("v_pk_add_f32 %0, %1, %2" : "=v"(d) : "v"(a), "v"(b));
  return d;
}
__device__ __forceinline__ v2f pk_mul(v2f a, v2f b) {
  v2f d;
  asm("v_pk_mul_f32 %0, %1, %2" : "=v"(d) : "v"(a), "v"(b));
  return d;
}

template <int CTRL>
__device__ __forceinline__ u64 dpp_u64(u64 v) {
  int lo = (int)(unsigned)v;
  int hi = (int)(unsigned)(v >> 32);
  int nlo = __builtin_amdgcn_update_dpp(lo, lo, CTRL, 0xF, 0xF, false);
  int nhi = __builtin_amdgcn_update_dpp(hi, hi, CTRL, 0xF, 0xF, false);
  return ((u64)(unsigned)nhi << 32) | (unsigned)nlo;
}
template <int CTRL>
__device__ __forceinline__ float dpp_f(float v) {
  int x = __float_as_int(v);
  return __int_as_float(__builtin_amdgcn_update_dpp(x, x, CTRL, 0xF, 0xF, false));
}

// Full-wave max reduce (key u64 + xyz payload) on VALU pipe; result in lane 63.
template <int CTRL>
__device__ __forceinline__ void red_step(u64& K, float& X, float& Y, float& Z) {
  u64 oK = dpp_u64<CTRL>(K);
  float oX = dpp_f<CTRL>(X), oY = dpp_f<CTRL>(Y), oZ = dpp_f<CTRL>(Z);
  if (oK > K) { K = oK; X = oX; Y = oY; Z = oZ; }
}
__device__ __forceinline__ void wave_max_payload(u64& K, float& X, float& Y, float& Z) {
  red_step<0x111>(K, X, Y, Z);  // row_shr:1
  red_step<0x112>(K, X, Y, Z);  // row_shr:2
  red_step<0x114>(K, X, Y, Z);  // row_shr:4
  red_step<0x118>(K, X, Y, Z);  // row_shr:8
  red_step<0x142>(K, X, Y, Z);  // row_bcast15
  red_step<0x143>(K, X, Y, Z);  // row_bcast31
}

// key-only wave max (for small-stage FPS)
__device__ __forceinline__ u64 wave_max_u64(u64 P) {
  u64 o;
  o = dpp_u64<0x111>(P); P = o > P ? o : P;
  o = dpp_u64<0x112>(P); P = o > P ? o : P;
  o = dpp_u64<0x114>(P); P = o > P ? o : P;
  o = dpp_u64<0x118>(P); P = o > P ? o : P;
  o = dpp_u64<0x142>(P); P = o > P ? o : P;
  o = dpp_u64<0x143>(P); P = o > P ? o : P;
  return P;
}

// ---------------------- bucketed FPS (stage 1) -----------------------------
// One block per batch. Phase A: 8x8x8 grid bin + LDS histogram + block scan +
// scatter to scratch (spatial sort). Phase B: each thread owns 32 contiguous
// sorted points (chunk) with bounding sphere; per iteration it either skips
// (conservative-exact bound) reusing its cached candidate, or updates dists
// and recomputes chunk argmax via packed u64 (tie -> smallest ORIGINAL index).
// Winner coords ride the DPP reduce as payload -> no global centroid fetch.
template <int N, int NPOINT, int T>
__global__ __launch_bounds__(T) void fps_bucket_kernel(
    const float* __restrict__ xyz, int* __restrict__ fidx,
    float* __restrict__ gsx, float* __restrict__ gsy,
    float* __restrict__ gsz, int* __restrict__ gsi) {
#pragma clang fp contract(off)
  constexpr int PT = N / T;    // points per chunk (32)
  constexpr int NP2 = PT / 2;
  constexpr int NW = T / 64;
  constexpr int NB = 512;      // 8x8x8 bins
  static_assert(T == NB, "one bin per thread");
  const int b = blockIdx.x;
  const int t = threadIdx.x;
  const int lane = t & 63;
  const int wv = t >> 6;
  const float* base = xyz + (size_t)b * N * 3;
  float* bsx = gsx + (size_t)b * N;
  float* bsy = gsy + (size_t)b * N;
  float* bsz = gsz + (size_t)b * N;
  int* bsi = gsi + (size_t)b * N;

  __shared__ int s_hist[NB];
  __shared__ int s_scan[NB];
  __shared__ float s_red[6][NW];
  __shared__ u64 s_key[2][NW];
  __shared__ float s_px[2][NW], s_py[2][NW], s_pz[2][NW];

  // ---- Phase A1: bounding box ----
  float mnx = 1e30f, mny = 1e30f, mnz = 1e30f;
  float mxx = -1e30f, mxy = -1e30f, mxz = -1e30f;
  for (int k = 0; k < PT; ++k) {
    int i = t + k * T;
    float x = base[i * 3 + 0], y = base[i * 3 + 1], z = base[i * 3 + 2];
    mnx = fminf(mnx, x); mny = fminf(mny, y); mnz = fminf(mnz, z);
    mxx = fmaxf(mxx, x); mxy = fmaxf(mxy, y); mxz = fmaxf(mxz, z);
  }
#pragma unroll
  for (int off = 1; off < 64; off <<= 1) {
    mnx = fminf(mnx, __shfl_xor(mnx, off));
    mny = fminf(mny, __shfl_xor(mny, off));
    mnz = fminf(mnz, __shfl_xor(mnz, off));
    mxx = fmaxf(mxx, __shfl_xor(mxx, off));
    mxy = fmaxf(mxy, __shfl_xor(mxy, off));
    mxz = fmaxf(mxz, __shfl_xor(mxz, off));
  }
  if (lane == 0) {
    s_red[0][wv] = mnx; s_red[1][wv] = mny; s_red[2][wv] = mnz;
    s_red[3][wv] = mxx; s_red[4][wv] = mxy; s_red[5][wv] = mxz;
  }
  s_hist[t] = 0;
  __syncthreads();
  mnx = s_red[0][0]; mny = s_red[1][0]; mnz = s_red[2][0];
  mxx = s_red[3][0]; mxy = s_red[4][0]; mxz = s_red[5][0];
#pragma unroll
  for (int w = 1; w < NW; ++w) {
    mnx = fminf(mnx, s_red[0][w]); mny = fminf(mny, s_red[1][w]);
    mnz = fminf(mnz, s_red[2][w]);
    mxx = fmaxf(mxx, s_red[3][w]); mxy = fmaxf(mxy, s_red[4][w]);
    mxz = fmaxf(mxz, s_red[5][w]);
  }
  const float fx = 8.0f / (mxx - mnx + 1e-5f);
  const float fy = 8.0f / (mxy - mny + 1e-5f);
  const float fz = 8.0f / (mxz - mnz + 1e-5f);

  // ---- A2: histogram ----
  for (int k = 0; k < PT; ++k) {
    int i = t + k * T;
    float x = base[i * 3 + 0], y = base[i * 3 + 1], z = base[i * 3 + 2];
    int cx = min(7, max(0, (int)((x - mnx) * fx)));
    int cy = min(7, max(0, (int)((y - mny) * fy)));
    int cz = min(7, max(0, (int)((z - mnz) * fz)));
    atomicAdd(&s_hist[(cx * 8 + cy) * 8 + cz], 1);
  }
  __syncthreads();

  // ---- A3: block exclusive scan over 512 bins (Hillis-Steele) ----
  s_scan[t] = s_hist[t];
  __syncthreads();
  for (int off = 1; off < NB; off <<= 1) {
    int v = (t >= off) ? s_scan[t - off] : 0;
    __syncthreads();
    s_scan[t] += v;
    __syncthreads();
  }
  s_hist[t] = s_scan[t] - s_hist[t];  // exclusive prefix = scatter cursor
  __syncthreads();

  // ---- A4: scatter (spatial sort). Within-cell order is nondeterministic,
  // but FPS ties break on ORIGINAL index via the packed key, so the selected
  // index sequence is invariant to within-cell ordering. ----
  for (int k = 0; k < PT; ++k) {
    int i = t + k * T;
    float x = base[i * 3 + 0], y = base[i * 3 + 1], z = base[i * 3 + 2];
    int cx = min(7, max(0, (int)((x - mnx) * fx)));
    int cy = min(7, max(0, (int)((y - mny) * fy)));
    int cz = min(7, max(0, (int)((z - mnz) * fz)));
    int pos = atomicAdd(&s_hist[(cx * 8 + cy) * 8 + cz], 1);
    bsx[pos] = x; bsy[pos] = y; bsz[pos] = z; bsi[pos] = i;
  }
  __threadfence();
  __syncthreads();

  // ---- A5: load my chunk (32 contiguous sorted points) ----
  v2f px[NP2], py[NP2], pz[NP2], dv[NP2];
  unsigned lo[PT];
#pragma unroll
  for (int k = 0; k < PT; ++k) {
    int pos = t * PT + k;
    float x = bsx[pos], y = bsy[pos], z = bsz[pos];
    px[k / 2][k & 1] = x; py[k / 2][k & 1] = y; pz[k / 2][k & 1] = z;
    dv[k / 2][k & 1] = 1e10f;
    lo[k] = (unsigned)(N - bsi[pos]);
  }
  // chunk bounding sphere
  float cmnx = 1e30f, cmny = 1e30f, cmnz = 1e30f;
  float cmxx = -1e30f, cmxy = -1e30f, cmxz = -1e30f;
#pragma unroll
  for (int k = 0; k < PT; ++k) {
    float x = px[k / 2][k & 1], y = py[k / 2][k & 1], z = pz[k / 2][k & 1];
    cmnx = fminf(cmnx, x); cmny = fminf(cmny, y); cmnz = fminf(cmnz, z);
    cmxx = fmaxf(cmxx, x); cmxy = fmaxf(cmxy, y); cmxz = fmaxf(cmxz, z);
  }
  const float ccx = 0.5f * (cmnx + cmxx);
  const float ccy = 0.5f * (cmny + cmxy);
  const float ccz = 0.5f * (cmnz + cmxz);
  float r2m = 0.f;
#pragma unroll
  for (int k = 0; k < PT; ++k) {
    float dx = px[k / 2][k & 1] - ccx, dy = py[k / 2][k & 1] - ccy,
          dz = pz[k / 2][k & 1] - ccz;
    r2m = fmaxf(r2m, dx * dx + dy * dy + dz * dz);
  }
  const float crad = sqrtf(r2m) * 1.0001f + 1e-7f;

  // cached candidate (valid after first update; first iter never skips)
  u64 ck = 0;
  float cbx = 0.f, cby = 0.f, cbz = 0.f, cmax = 1e10f;

  // iteration-0 centroid = original point 0
  float cenx = base[0], ceny = base[1], cenz = base[2];
  int far = 0;
  int p = 0;

  for (int it = 0; it < NPOINT; ++it) {
    if (t == 0) fidx[b * NPOINT + it] = far;

    // conservative-exact skip test (margins >> fp32 error)
    float ddx = ccx - cenx, ddy = ccy - ceny, ddz = ccz - cenz;
    float dc = sqrtf(ddx * ddx + ddy * ddy + ddz * ddz);
    float lb = dc - crad;
    bool skip = (lb > 0.f) && (lb * lb * 0.9999f >= cmax * 1.0001f);
    if (!skip) {
      const float nx = -cenx, ny = -ceny, nz = -cenz;
      const v2f c2x = {nx, nx}, c2y = {ny, ny}, c2z = {nz, nz};
      u64 bkA = 0, bkB = 0;
      float axA = 0, ayA = 0, azA = 0, axB = 0, ayB = 0, azB = 0;
#pragma unroll
      for (int j = 0; j < NP2; ++j) {
        v2f dx = pk_add(px[j], c2x);
        v2f dy = pk_add(py[j], c2y);
        v2f dz = pk_add(pz[j], c2z);
        v2f xx = pk_mul(dx, dx);
        v2f yy = pk_mul(dy, dy);
        v2f zz = pk_mul(dz, dz);
        v2f s = pk_add(xx, yy);
        v2f d = pk_add(s, zz);
        float nd0 = fminf(dv[j][0], d[0]);
        float nd1 = fminf(dv[j][1], d[1]);
        dv[j][0] = nd0; dv[j][1] = nd1;
        u64 p0 = ((u64)__float_as_uint(nd0) << 32) | lo[2 * j];
        if (p0 > bkA) { bkA = p0; axA = px[j][0]; ayA = py[j][0]; azA = pz[j][0]; }
        u64 p1 = ((u64)__float_as_uint(nd1) << 32) | lo[2 * j + 1];
        if (p1 > bkB) { bkB = p1; axB = px[j][1]; ayB = py[j][1]; azB = pz[j][1]; }
      }
      if (bkB > bkA) { bkA = bkB; axA = axB; ayA = ayB; azA = azB; }
      ck = bkA; cbx = axA; cby = ayA; cbz = azA;
      cmax = __uint_as_float((unsigned)(bkA >> 32));
    }

    // contribute cached candidate; DPP reduce with coord payload
    u64 K = ck;
    float X = cbx, Y = cby, Z = cbz;
    wave_max_payload(K, X, Y, Z);
    if (lane == 63) {
      s_key[p][wv] = K; s_px[p][wv] = X; s_py[p][wv] = Y; s_pz[p][wv] = Z;
    }
    __syncthreads();
    u64 bb = s_key[p][0];
    int m = 0;
#pragma unroll
    for (int w = 1; w < NW; ++w) {
      u64 v = s_key[p][w];
      if (v > bb) { bb = v; m = w; }
    }
    far = N - (int)(unsigned)(bb & 0xffffffffull);
    cenx = s_px[p][m]; ceny = s_py[p][m]; cenz = s_pz[p][m];
    p ^= 1;
  }
}

// ------------------------ brute FPS (stages 2-4) ---------------------------
template <int N, int NPOINT, int T, bool XYZ_IN_LDS>
__global__ __launch_bounds__(T) void fps_kernel(const float* __restrict__ xyz,
                                                int* __restrict__ fidx) {
#pragma clang fp contract(off)
  constexpr int PT = N / T;
  static_assert(PT % 2 == 0, "PT even");
  constexpr int NP2 = PT / 2;
  constexpr int NW = T / 64;
  constexpr int NCH = (NP2 >= 4) ? 4 : NP2;
  constexpr int CW = NP2 / NCH;
  constexpr int LN = XYZ_IN_LDS ? N : 1;
  const int b = blockIdx.x;
  const int t = threadIdx.x;
  const int lane = t & 63;
  const int wv = t >> 6;
  const float* base = xyz + (size_t)b * N * 3;

  v2f px[NP2], py[NP2], pz[NP2], dv[NP2];
  __shared__ __align__(16) u64 s_pack[2][NW];
  __shared__ float s_x[LN], s_y[LN], s_z[LN];

#pragma unroll
  for (int j = 0; j < NP2; ++j) {
    int i0 = t + (2 * j) * T;
    int i1 = t + (2 * j + 1) * T;
    px[j][0] = base[i0 * 3 + 0]; py[j][0] = base[i0 * 3 + 1];
    pz[j][0] = base[i0 * 3 + 2];
    px[j][1] = base[i1 * 3 + 0]; py[j][1] = base[i1 * 3 + 1];
    pz[j][1] = base[i1 * 3 + 2];
    dv[j][0] = 1e10f; dv[j][1] = 1e10f;
    if constexpr (XYZ_IN_LDS) {
      s_x[i0] = px[j][0]; s_y[i0] = py[j][0]; s_z[i0] = pz[j][0];
      s_x[i1] = px[j][1]; s_y[i1] = py[j][1]; s_z[i1] = pz[j][1];
    }
  }
  __syncthreads();

  int far = 0;
  int p = 0;
  for (int it = 0; it < NPOINT; ++it) {
    if (t == 0) fidx[b * NPOINT + it] = far;
    float cx, cy, cz;
    if constexpr (XYZ_IN_LDS) {
      cx = s_x[far]; cy = s_y[far]; cz = s_z[far];
    } else {
      cx = base[far * 3 + 0]; cy = base[far * 3 + 1]; cz = base[far * 3 + 2];
    }
    const float nx = -cx, ny = -cy, nz = -cz;
    const v2f c2x = {nx, nx}, c2y = {ny, ny}, c2z = {nz, nz};

    float best[NCH];
    int bk[NCH];
#pragma unroll
    for (int q = 0; q < NCH; ++q) { best[q] = -1.0f; bk[q] = 0; }

#pragma unroll
    for (int j = 0; j < NP2; ++j) {
      v2f dx = pk_add(px[j], c2x);
      v2f dy = pk_add(py[j], c2y);
      v2f dz = pk_add(pz[j], c2z);
      v2f xx = pk_mul(dx, dx);
      v2f yy = pk_mul(dy, dy);
      v2f zz = pk_mul(dz, dz);
      v2f s = pk_add(xx, yy);
      v2f d = pk_add(s, zz);
      v2f nd;
      nd[0] = fminf(dv[j][0], d[0]);
      nd[1] = fminf(dv[j][1], d[1]);
      dv[j] = nd;
      const int q = j / CW;
      if (nd[0] > best[q]) { best[q] = nd[0]; bk[q] = 2 * j; }
      if (nd[1] > best[q]) { best[q] = nd[1]; bk[q] = 2 * j + 1; }
    }
    float bb = best[0];
    int kk = bk[0];
#pragma unroll
    for (int q = 1; q < NCH; ++q) {
      if (best[q] > bb) { bb = best[q]; kk = bk[q]; }
    }
    int idx = t + kk * T;
    u64 P = ((u64)__float_as_uint(bb) << 32) | (unsigned)(N - idx);
    P = wave_max_u64(P);
    if (lane == 63) s_pack[p][wv] = P;
    __syncthreads();
    u64 bbp = s_pack[p][0];
#pragma unroll
    for (int w = 1; w < NW; ++w) {
      u64 v = s_pack[p][w];
      bbp = v > bbp ? v : bbp;
    }
    far = N - (int)(unsigned)(bbp & 0xffffffffull);
    p ^= 1;
  }
}

// --------------------------- gather new_xyz --------------------------------
__global__ void gather_xyz_kernel(const float* __restrict__ xyz,
                                  const int* __restrict__ fidx,
                                  float* __restrict__ out, int N, int S) {
  int s = blockIdx.x * blockDim.x + threadIdx.x;
  int b = blockIdx.y;
  if (s < S) {
    int i = fidx[b * S + s];
    out[((size_t)(b * S + s)) * 3 + 0] = xyz[((size_t)(b * N + i)) * 3 + 0];
    out[((size_t)(b * S + s)) * 3 + 1] = xyz[((size_t)(b * N + i)) * 3 + 1];
    out[((size_t)(b * S + s)) * 3 + 2] = xyz[((size_t)(b * N + i)) * 3 + 2];
  }
}

// ----------------------------- ball query ----------------------------------
template <int N, int NS>
__global__ __launch_bounds__(256) void ball_query_kernel(
    const float* __restrict__ xyz, const float* __restrict__ new_xyz,
    int* __restrict__ nidx, int S, float r2) {
#pragma clang fp contract(off)
  const int wv = threadIdx.x >> 6;
  const int lane = threadIdx.x & 63;
  const int b = blockIdx.y;
  const int s = blockIdx.x * 4 + wv;
  __shared__ int s_idx[4][NS];
  const float* base = xyz + (size_t)b * N * 3;

  float cx = new_xyz[((size_t)(b * S + s)) * 3 + 0];
  float cy = new_xyz[((size_t)(b * S + s)) * 3 + 1];
  float cz = new_xyz[((size_t)(b * S + s)) * 3 + 2];
  float sc = (cx * cx + cy * cy) + cz * cz;

  int found = 0;
  for (int i0 = 0; i0 < N && found < NS; i0 += 64) {
    int i = i0 + lane;
    float x = base[i * 3 + 0];
    float y = base[i * 3 + 1];
    float z = base[i * 3 + 2];
    float sx = (x * x + y * y) + z * z;
    float dt = (cx * x + cy * y) + cz * z;
    float d2 = (sc + sx) - 2.0f * dt;
    bool inb = d2 < r2;
    unsigned long long m = __ballot(inb);
    if (inb) {
      int pos = found + __popcll(m & ((1ull << lane) - 1));
      if (pos < NS) s_idx[wv][pos] = i;
    }
    found += __popcll(m);
  }
  __syncthreads();
  int fcnt = found < NS ? found : NS;
  int first = s_idx[wv][0];
  int* outp = nidx + ((size_t)(b * S + s)) * NS;
  for (int j = lane; j < NS; j += 64) outp[j] = (j < fcnt) ? s_idx[wv][j] : first;
}

// --------------------------- fused group MLP -------------------------------
template <int R, int RG, int CG, int CMAXP, int CIN, int COUT>
__device__ __forceinline__ void mlp_layer(float* act, const float* __restrict__ w,
                                          const float* __restrict__ bias, int tid) {
  constexpr int RPT = R / RG;
  constexpr int CPT = COUT / CG;
  static_assert(RG * CG == 256, "thread grid");
  const int rg = tid / CG;
  const int cg = tid % CG;

  float acc[RPT][CPT];
#pragma unroll
  for (int rr = 0; rr < RPT; ++rr)
#pragma unroll
    for (int cc = 0; cc < CPT; ++cc) acc[rr][cc] = 0.f;

  constexpr int K4 = (CIN / 4) * 4;
  for (int k = 0; k < K4; k += 4) {
    float4 a[RPT];
#pragma unroll
    for (int rr = 0; rr < RPT; ++rr)
      a[rr] = *(const float4*)(&act[(rg * RPT + rr) * CMAXP + k]);
    float wvv[4][CPT];
#pragma unroll
    for (int kk = 0; kk < 4; ++kk)
#pragma unroll
      for (int cc = 0; cc < CPT; ++cc)
        wvv[kk][cc] = w[(size_t)(k + kk) * COUT + cg + cc * CG];
#pragma unroll
    for (int rr = 0; rr < RPT; ++rr) {
      float4 av = a[rr];
#pragma unroll
      for (int cc = 0; cc < CPT; ++cc) {
        acc[rr][cc] += av.x * wvv[0][cc];
        acc[rr][cc] += av.y * wvv[1][cc];
        acc[rr][cc] += av.z * wvv[2][cc];
        acc[rr][cc] += av.w * wvv[3][cc];
      }
    }
  }
#pragma unroll 1
  for (int k = K4; k < CIN; ++k) {
    float wvv[CPT];
#pragma unroll
    for (int cc = 0; cc < CPT; ++cc) wvv[cc] = w[(size_t)k * COUT + cg + cc * CG];
#pragma unroll
    for (int rr = 0; rr < RPT; ++rr) {
      float av = act[(rg * RPT + rr) * CMAXP + k];
#pragma unroll
      for (int cc = 0; cc < CPT; ++cc) acc[rr][cc] += av * wvv[cc];
    }
  }
  __syncthreads();
#pragma unroll
  for (int rr = 0; rr < RPT; ++rr)
#pragma unroll
    for (int cc = 0; cc < CPT; ++cc) {
      int co = cg + cc * CG;
      float v = acc[rr][cc] + bias[co];
      act[(rg * RPT + rr) * CMAXP + co] = fmaxf(v, 0.f);
    }
  __syncthreads();
}

template <int NS, int G, int CPREV, int CO0, int CO1, int CO2, int RG, int CG, int CMAXP>
__global__ __launch_bounds__(256) void group_mlp_kernel(
    const float* __restrict__ xyz, const float* __restrict__ new_xyz,
    const float* __restrict__ feats, const int* __restrict__ nidx,
    const float* __restrict__ w0, const float* __restrict__ b0,
    const float* __restrict__ w1, const float* __restrict__ b1,
    const float* __restrict__ w2, const float* __restrict__ b2,
    float* __restrict__ out, int N, int S, float radius) {
  constexpr int R = NS * G;
  constexpr int CIN = 3 + CPREV;
  __shared__ __align__(16) float act[R * CMAXP];
  const int tid = threadIdx.x;
  const int b = blockIdx.y;
  const int s0 = blockIdx.x * G;

  for (int i = tid; i < R * CIN; i += 256) {
    int row = i / CIN;
    int ch = i - row * CIN;
    int g = row / NS;
    int j = row - g * NS;
    int sidx = s0 + g;
    int n = nidx[((size_t)(b * S + sidx)) * NS + j];
    float v;
    if constexpr (CPREV == 0) {
      v = (xyz[((size_t)(b * N + n)) * 3 + ch] -
           new_xyz[((size_t)(b * S + sidx)) * 3 + ch]) /
          radius;
    } else {
      if (ch < 3) {
        v = (xyz[((size_t)(b * N + n)) * 3 + ch] -
             new_xyz[((size_t)(b * S + sidx)) * 3 + ch]) /
            radius;
      } else {
        v = feats[((size_t)(b * N + n)) * CPREV + (ch - 3)];
      }
    }
    act[row * CMAXP + ch] = v;
  }
  __syncthreads();

  mlp_layer<R, RG, CG, CMAXP, CIN, CO0>(act, w0, b0, tid);
  mlp_layer<R, RG, CG, CMAXP, CO0, CO1>(act, w1, b1, tid);
  mlp_layer<R, RG, CG, CMAXP, CO1, CO2>(act, w2, b2, tid);

  for (int i = tid; i < G * CO2; i += 256) {
    int g = i / CO2;
    int co = i - g * CO2;
    float m = act[(g * NS) * CMAXP + co];
    for (int j = 1; j < NS; ++j) m = fmaxf(m, act[(g * NS + j) * CMAXP + co]);
    out[((size_t)(b * S + s0 + g)) * CO2 + co] = m;
  }
}

// ---------------------------------------------------------------------------
extern "C" void kernel_launch(void* const* d_in, const int* in_sizes, int n_in,
                              void* d_out, int out_size, void* d_ws, size_t ws_size,
                              hipStream_t stream) {
  (void)in_sizes; (void)n_in; (void)out_size; (void)ws_size;
  const float* pc = (const float*)d_in[0];
  const float* W[4][3];
  const float* Bb[4][3];
  for (int s = 0; s < 4; ++s)
    for (int l = 0; l < 3; ++l) {
      W[s][l] = (const float*)d_in[1 + s * 6 + l * 2];
      Bb[s][l] = (const float*)d_in[2 + s * 6 + l * 2];
    }

  // workspace layout (bytes): fidx 32KB | nidx 2MB | xyzA 96KB | xyzB 96KB |
  // featA 4MB | featB 4MB. Stage-1 sort scratch (1MB) aliases featB (featB is
  // first written by stage-2 group_mlp, after stage-1 FPS has completed).
  char* wsp = (char*)d_ws;
  int* fidx = (int*)wsp;
  int* nidx = (int*)(wsp + (32 << 10));
  float* xyzA = (float*)(wsp + (32 << 10) + (2 << 20));
  float* xyzB = xyzA + B_SZ * 2048 * 3;
  float* featA = xyzB + B_SZ * 2048 * 3;
  float* featB = featA + B_SZ * 2048 * 128;
  float* gsx = featB;                    // 4*16384 floats
  float* gsy = gsx + B_SZ * 16384;
  float* gsz = gsy + B_SZ * 16384;
  int* gsi = (int*)(gsz + B_SZ * 16384);
  float* oxyz = (float*)d_out;           // [4,256,3]
  float* ofeat = oxyz + B_SZ * 256 * 3;  // [4,256,512]

  // ---------------- Stage 1: N=16384 -> S=2048, r=0.2, ns=64, 3->64->64->128
  hipLaunchKernelGGL((fps_bucket_kernel<16384, 2048, 512>), dim3(B_SZ), dim3(512), 0, stream,
                     pc, fidx, gsx, gsy, gsz, gsi);
  hipLaunchKernelGGL(gather_xyz_kernel, dim3(32, B_SZ), dim3(64), 0, stream,
                     pc, fidx, xyzA, 16384, 2048);
  hipLaunchKernelGGL((ball_query_kernel<16384, 64>), dim3(512, B_SZ), dim3(256), 0, stream,
                     pc, xyzA, nidx, 2048, (float)(0.2 * 0.2));
  hipLaunchKernelGGL((group_mlp_kernel<64, 1, 0, 64, 64, 128, 8, 32, 128>),
                     dim3(2048, B_SZ), dim3(256), 0, stream,
                     pc, xyzA, (const float*)nullptr, nidx,
                     W[0][0], Bb[0][0], W[0][1], Bb[0][1], W[0][2], Bb[0][2],
                     featA, 16384, 2048, 0.2f);

  // ---------------- Stage 2: N=2048 -> S=1024, r=0.4, ns=32, 131->128->128->256
  hipLaunchKernelGGL((fps_kernel<2048, 1024, 512, true>), dim3(B_SZ), dim3(512), 0, stream,
                     xyzA, fidx);
  hipLaunchKernelGGL(gather_xyz_kernel, dim3(16, B_SZ), dim3(64), 0, stream,
                     xyzA, fidx, xyzB, 2048, 1024);
  hipLaunchKernelGGL((ball_query_kernel<2048, 32>), dim3(256, B_SZ), dim3(256), 0, stream,
                     xyzA, xyzB, nidx, 1024, (float)(0.4 * 0.4));
  hipLaunchKernelGGL((group_mlp_kernel<32, 1, 128, 128, 128, 256, 4, 64, 256>),
                     dim3(1024, B_SZ), dim3(256), 0, stream,
                     xyzA, xyzB, featA, nidx,
                     W[1][0], Bb[1][0], W[1][1], Bb[1][1], W[1][2], Bb[1][2],
                     featB, 2048, 1024, 0.4f);

  // ---------------- Stage 3: N=1024 -> S=512, r=0.6, ns=16, 259->256->256->512
  hipLaunchKernelGGL((fps_kernel<1024, 512, 256, true>), dim3(B_SZ), dim3(256), 0, stream,
                     xyzB, fidx);
  hipLaunchKernelGGL(gather_xyz_kernel, dim3(8, B_SZ), dim3(64), 0, stream,
                     xyzB, fidx, xyzA, 1024, 512);
  hipLaunchKernelGGL((ball_query_kernel<1024, 16>), dim3(128, B_SZ), dim3(256), 0, stream,
                     xyzB, xyzA, nidx, 512, (float)(0.6 * 0.6));
  hipLaunchKernelGGL((group_mlp_kernel<16, 1, 256, 256, 256, 512, 2, 128, 512>),
                     dim3(512, B_SZ), dim3(256), 0, stream,
                     xyzB, xyzA, featB, nidx,
                     W[2][0], Bb[2][0], W[2][1], Bb[2][1], W[2][2], Bb[2][2],
                     featA, 1024, 512, 0.6f);

  // ---------------- Stage 4: N=512 -> S=256, r=1.2, ns=8, 515->512->512->512
  hipLaunchKernelGGL((fps_kernel<512, 256, 256, true>), dim3(B_SZ), dim3(256), 0, stream,
                     xyzA, fidx);
  hipLaunchKernelGGL(gather_xyz_kernel, dim3(4, B_SZ), dim3(64), 0, stream,
                     xyzA, fidx, oxyz, 512, 256);
  hipLaunchKernelGGL((ball_query_kernel<512, 8>), dim3(64, B_SZ), dim3(256), 0, stream,
                     xyzA, oxyz, nidx, 256, (float)(1.2 * 1.2));
  hipLaunchKernelGGL((group_mlp_kernel<8, 2, 512, 512, 512, 512, 2, 128, 516>),
                     dim3(128, B_SZ), dim3(256), 0, stream,
                     xyzA, oxyz, featA, nidx,
                     W[3][0], Bb[3][0], W[3][1], Bb[3][1], W[3][2], Bb[3][2],
                     ofeat, 512, 256, 1.2f);
}

// Round 7
// 5180.537 us; speedup vs baseline: 1.4532x; 1.4532x over previous
//
#include <hip/hip_runtime.h>
#include <hip/hip_bf16.h>

// ---------------------------------------------------------------------------
// PointNet++ encoder (4 SA stages) for MI355X.
// Stage pipeline: FPS -> gather new_xyz -> ball query -> fused group+MLP+maxpool.
// FPS / ball-query distance math matches numpy per-op IEEE semantics exactly
// (argmax selection must be exact; xyz output is raw copies).
// ---------------------------------------------------------------------------

#define B_SZ 4

typedef float v2f __attribute__((ext_vector_type(2)));
typedef unsigned long long u64;

// Packed-FP32 helpers (VOP3P). Each half is a plain IEEE f32 op, so results
// are bitwise identical to scalar v_add_f32/v_mul_f32.
__device__ __forceinline__ v2f pk_add(v2f a, v2f b) {
  v2f d;
  asm("v_pk_add_f32 %0, %1, %2" : "=v"(d) : "v"(a), "v"(b));
  return d;
}
__device__ __forceinline__ v2f pk_mul(v2f a, v2f b) {
  v2f d;
  asm("v_pk_mul_f32 %0, %1, %2" : "=v"(d) : "v"(a), "v"(b));
  return d;
}

template <int CTRL>
__device__ __forceinline__ u64 dpp_u64(u64 v) {
  int lo = (int)(unsigned)v;
  int hi = (int)(unsigned)(v >> 32);
  int nlo = __builtin_amdgcn_update_dpp(lo, lo, CTRL, 0xF, 0xF, false);
  int nhi = __builtin_amdgcn_update_dpp(hi, hi, CTRL, 0xF, 0xF, false);
  return ((u64)(unsigned)nhi << 32) | (unsigned)nlo;
}

// Full-wave (64-lane) max reduce on VALU pipe; result valid in lane 63.
__device__ __forceinline__ u64 wave_max_u64(u64 P) {
  u64 o;
  o = dpp_u64<0x111>(P); P = o > P ? o : P;  // row_shr:1
  o = dpp_u64<0x112>(P); P = o > P ? o : P;  // row_shr:2
  o = dpp_u64<0x114>(P); P = o > P ? o : P;  // row_shr:4
  o = dpp_u64<0x118>(P); P = o > P ? o : P;  // row_shr:8
  o = dpp_u64<0x142>(P); P = o > P ? o : P;  // row_bcast15
  o = dpp_u64<0x143>(P); P = o > P ? o : P;  // row_bcast31
  return P;
}

// ------------------------------- FPS ---------------------------------------
// One block per batch; ONE barrier per iteration.
// Hot loop per point-pair (11 instr): 8 pk ops for the exact distance
// (contract-off op order: sub,sub,sub,mul,mul,mul,add,add), 2 scalar fmin for
// the running min-dist, 1 v_max3 for the value-only max track (4 round-robin
// accumulators). The argmax INDEX is recovered once per iteration by a
// descending rescan for dv[k]==m (first occurrence = smallest index, matching
// jnp.argmax). Packed u64 (dist_bits<<32 | N-idx) -> DPP wave reduce -> NW
// wave results combined by a redundant LDS scan (double-buffered, 1 barrier).
// __launch_bounds__(T, T/256) declares the true min waves/EU so the register
// allocator gets the full 256-VGPR budget (else point arrays land in AGPRs
// and every access pays a v_accvgpr_read).
template <int N, int NPOINT, int T, bool XYZ_IN_LDS>
__global__ __launch_bounds__(T, (T / 256 > 0) ? T / 256 : 1) void fps_kernel(
    const float* __restrict__ xyz, int* __restrict__ fidx) {
#pragma clang fp contract(off)
  constexpr int PT = N / T;
  static_assert(PT % 2 == 0, "PT even");
  constexpr int NP2 = PT / 2;
  constexpr int NW = T / 64;
  constexpr int NACC = (NP2 >= 4) ? 4 : NP2;
  constexpr int LN = XYZ_IN_LDS ? N : 1;
  const int b = blockIdx.x;
  const int t = threadIdx.x;
  const int lane = t & 63;
  const int wv = t >> 6;
  const float* base = xyz + (size_t)b * N * 3;

  v2f px[NP2], py[NP2], pz[NP2], dv[NP2];
  __shared__ __align__(16) u64 s_pack[2][NW];
  __shared__ float s_x[LN], s_y[LN], s_z[LN];

#pragma unroll
  for (int j = 0; j < NP2; ++j) {
    int i0 = t + (2 * j) * T;
    int i1 = t + (2 * j + 1) * T;
    px[j][0] = base[i0 * 3 + 0]; py[j][0] = base[i0 * 3 + 1];
    pz[j][0] = base[i0 * 3 + 2];
    px[j][1] = base[i1 * 3 + 0]; py[j][1] = base[i1 * 3 + 1];
    pz[j][1] = base[i1 * 3 + 2];
    dv[j][0] = 1e10f; dv[j][1] = 1e10f;
    if constexpr (XYZ_IN_LDS) {
      s_x[i0] = px[j][0]; s_y[i0] = py[j][0]; s_z[i0] = pz[j][0];
      s_x[i1] = px[j][1]; s_y[i1] = py[j][1]; s_z[i1] = pz[j][1];
    }
  }
  __syncthreads();

  int far = 0;
  int p = 0;
  for (int it = 0; it < NPOINT; ++it) {
    if (t == 0) fidx[b * NPOINT + it] = far;
    float cx, cy, cz;
    if constexpr (XYZ_IN_LDS) {
      cx = s_x[far]; cy = s_y[far]; cz = s_z[far];
    } else {
      cx = base[far * 3 + 0]; cy = base[far * 3 + 1]; cz = base[far * 3 + 2];
    }
    // (p - c) computed as p + (-c): bitwise identical to IEEE subtraction.
    const float nx = -cx, ny = -cy, nz = -cz;
    const v2f c2x = {nx, nx}, c2y = {ny, ny}, c2z = {nz, nz};

    float mx[NACC];
#pragma unroll
    for (int q = 0; q < NACC; ++q) mx[q] = -1.0f;

#pragma unroll
    for (int j = 0; j < NP2; ++j) {
      v2f dx = pk_add(px[j], c2x);
      v2f dy = pk_add(py[j], c2y);
      v2f dz = pk_add(pz[j], c2z);
      v2f xx = pk_mul(dx, dx);
      v2f yy = pk_mul(dy, dy);
      v2f zz = pk_mul(dz, dz);
      v2f s = pk_add(xx, yy);
      v2f d = pk_add(s, zz);
      float nd0 = fminf(dv[j][0], d[0]);
      float nd1 = fminf(dv[j][1], d[1]);
      dv[j][0] = nd0; dv[j][1] = nd1;
      const int q = j % NACC;  // compile-time (loop unrolled)
      mx[q] = fmaxf(fmaxf(nd0, nd1), mx[q]);  // -> v_max3_f32
    }
    // fold accumulators (value only)
    float m = mx[0];
#pragma unroll
    for (int q = 1; q < NACC; ++q) m = fmaxf(m, mx[q]);

    // rescan for FIRST k with dv[k]==m (descending overwrite -> smallest idx)
    int bk = 0;
#pragma unroll
    for (int j = NP2 - 1; j >= 0; --j) {
      if (dv[j][1] == m) bk = 2 * j + 1;
      if (dv[j][0] == m) bk = 2 * j;
    }

    int idx = t + bk * T;
    u64 P = ((u64)__float_as_uint(m) << 32) | (unsigned)(N - idx);
    P = wave_max_u64(P);
    if (lane == 63) s_pack[p][wv] = P;
    __syncthreads();
    u64 bbp = s_pack[p][0];
#pragma unroll
    for (int w = 1; w < NW; ++w) {
      u64 v = s_pack[p][w];
      bbp = v > bbp ? v : bbp;
    }
    far = N - (int)(unsigned)(bbp & 0xffffffffull);
    p ^= 1;
  }
}

// --------------------------- gather new_xyz --------------------------------
__global__ void gather_xyz_kernel(const float* __restrict__ xyz,
                                  const int* __restrict__ fidx,
                                  float* __restrict__ out, int N, int S) {
  int s = blockIdx.x * blockDim.x + threadIdx.x;
  int b = blockIdx.y;
  if (s < S) {
    int i = fidx[b * S + s];
    out[((size_t)(b * S + s)) * 3 + 0] = xyz[((size_t)(b * N + i)) * 3 + 0];
    out[((size_t)(b * S + s)) * 3 + 1] = xyz[((size_t)(b * N + i)) * 3 + 1];
    out[((size_t)(b * S + s)) * 3 + 2] = xyz[((size_t)(b * N + i)) * 3 + 2];
  }
}

// ----------------------------- ball query ----------------------------------
// One wave per query point. Scan N points in 64-chunks; ballot-ordered append
// of in-ball indices (ascending index = reference's sort semantics); pad with
// first neighbor. d2 formula replicates (|c|^2 + |x|^2) - 2*dot, contract off.
template <int N, int NS>
__global__ __launch_bounds__(256) void ball_query_kernel(
    const float* __restrict__ xyz, const float* __restrict__ new_xyz,
    int* __restrict__ nidx, int S, float r2) {
#pragma clang fp contract(off)
  const int wv = threadIdx.x >> 6;
  const int lane = threadIdx.x & 63;
  const int b = blockIdx.y;
  const int s = blockIdx.x * 4 + wv;
  __shared__ int s_idx[4][NS];
  const float* base = xyz + (size_t)b * N * 3;

  float cx = new_xyz[((size_t)(b * S + s)) * 3 + 0];
  float cy = new_xyz[((size_t)(b * S + s)) * 3 + 1];
  float cz = new_xyz[((size_t)(b * S + s)) * 3 + 2];
  float sc = (cx * cx + cy * cy) + cz * cz;

  int found = 0;
  for (int i0 = 0; i0 < N && found < NS; i0 += 64) {
    int i = i0 + lane;
    float x = base[i * 3 + 0];
    float y = base[i * 3 + 1];
    float z = base[i * 3 + 2];
    float sx = (x * x + y * y) + z * z;
    float dt = (cx * x + cy * y) + cz * z;
    float d2 = (sc + sx) - 2.0f * dt;
    bool inb = d2 < r2;
    unsigned long long m = __ballot(inb);
    if (inb) {
      int pos = found + __popcll(m & ((1ull << lane) - 1));
      if (pos < NS) s_idx[wv][pos] = i;
    }
    found += __popcll(m);
  }
  __syncthreads();
  int fcnt = found < NS ? found : NS;
  int first = s_idx[wv][0];
  int* outp = nidx + ((size_t)(b * S + s)) * NS;
  for (int j = lane; j < NS; j += 64) outp[j] = (j < fcnt) ? s_idx[wv][j] : first;
}

// --------------------------- fused group MLP -------------------------------
// act[R][CMAXP] in LDS holds activations in-place across the 3 layers.
// Thread grid RG x CG; each thread owns RPT rows x CPT cols; W streamed from
// L1/L2 (each W element feeds RPT FMAs).
template <int R, int RG, int CG, int CMAXP, int CIN, int COUT>
__device__ __forceinline__ void mlp_layer(float* act, const float* __restrict__ w,
                                          const float* __restrict__ bias, int tid) {
  constexpr int RPT = R / RG;
  constexpr int CPT = COUT / CG;
  static_assert(RG * CG == 256, "thread grid");
  const int rg = tid / CG;
  const int cg = tid % CG;

  float acc[RPT][CPT];
#pragma unroll
  for (int rr = 0; rr < RPT; ++rr)
#pragma unroll
    for (int cc = 0; cc < CPT; ++cc) acc[rr][cc] = 0.f;

  constexpr int K4 = (CIN / 4) * 4;
  for (int k = 0; k < K4; k += 4) {
    float4 a[RPT];
#pragma unroll
    for (int rr = 0; rr < RPT; ++rr)
      a[rr] = *(const float4*)(&act[(rg * RPT + rr) * CMAXP + k]);
    float wvv[4][CPT];
#pragma unroll
    for (int kk = 0; kk < 4; ++kk)
#pragma unroll
      for (int cc = 0; cc < CPT; ++cc)
        wvv[kk][cc] = w[(size_t)(k + kk) * COUT + cg + cc * CG];
#pragma unroll
    for (int rr = 0; rr < RPT; ++rr) {
      float4 av = a[rr];
#pragma unroll
      for (int cc = 0; cc < CPT; ++cc) {
        acc[rr][cc] += av.x * wvv[0][cc];
        acc[rr][cc] += av.y * wvv[1][cc];
        acc[rr][cc] += av.z * wvv[2][cc];
        acc[rr][cc] += av.w * wvv[3][cc];
      }
    }
  }
#pragma unroll 1
  for (int k = K4; k < CIN; ++k) {
    float wvv[CPT];
#pragma unroll
    for (int cc = 0; cc < CPT; ++cc) wvv[cc] = w[(size_t)k * COUT + cg + cc * CG];
#pragma unroll
    for (int rr = 0; rr < RPT; ++rr) {
      float av = act[(rg * RPT + rr) * CMAXP + k];
#pragma unroll
      for (int cc = 0; cc < CPT; ++cc) acc[rr][cc] += av * wvv[cc];
    }
  }
  __syncthreads();  // all reads of act done before in-place overwrite
#pragma unroll
  for (int rr = 0; rr < RPT; ++rr)
#pragma unroll
    for (int cc = 0; cc < CPT; ++cc) {
      int co = cg + cc * CG;
      float v = acc[rr][cc] + bias[co];
      act[(rg * RPT + rr) * CMAXP + co] = fmaxf(v, 0.f);
    }
  __syncthreads();
}

template <int NS, int G, int CPREV, int CO0, int CO1, int CO2, int RG, int CG, int CMAXP>
__global__ __launch_bounds__(256) void group_mlp_kernel(
    const float* __restrict__ xyz, const float* __restrict__ new_xyz,
    const float* __restrict__ feats, const int* __restrict__ nidx,
    const float* __restrict__ w0, const float* __restrict__ b0,
    const float* __restrict__ w1, const float* __restrict__ b1,
    const float* __restrict__ w2, const float* __restrict__ b2,
    float* __restrict__ out, int N, int S, float radius) {
  constexpr int R = NS * G;
  constexpr int CIN = 3 + CPREV;
  __shared__ __align__(16) float act[R * CMAXP];
  const int tid = threadIdx.x;
  const int b = blockIdx.y;
  const int s0 = blockIdx.x * G;

  for (int i = tid; i < R * CIN; i += 256) {
    int row = i / CIN;
    int ch = i - row * CIN;
    int g = row / NS;
    int j = row - g * NS;
    int sidx = s0 + g;
    int n = nidx[((size_t)(b * S + sidx)) * NS + j];
    float v;
    if constexpr (CPREV == 0) {
      v = (xyz[((size_t)(b * N + n)) * 3 + ch] -
           new_xyz[((size_t)(b * S + sidx)) * 3 + ch]) /
          radius;
    } else {
      if (ch < 3) {
        v = (xyz[((size_t)(b * N + n)) * 3 + ch] -
             new_xyz[((size_t)(b * S + sidx)) * 3 + ch]) /
            radius;
      } else {
        v = feats[((size_t)(b * N + n)) * CPREV + (ch - 3)];
      }
    }
    act[row * CMAXP + ch] = v;
  }
  __syncthreads();

  mlp_layer<R, RG, CG, CMAXP, CIN, CO0>(act, w0, b0, tid);
  mlp_layer<R, RG, CG, CMAXP, CO0, CO1>(act, w1, b1, tid);
  mlp_layer<R, RG, CG, CMAXP, CO1, CO2>(act, w2, b2, tid);

  for (int i = tid; i < G * CO2; i += 256) {
    int g = i / CO2;
    int co = i - g * CO2;
    float m = act[(g * NS) * CMAXP + co];
    for (int j = 1; j < NS; ++j) m = fmaxf(m, act[(g * NS + j) * CMAXP + co]);
    out[((size_t)(b * S + s0 + g)) * CO2 + co] = m;
  }
}

// ---------------------------------------------------------------------------
extern "C" void kernel_launch(void* const* d_in, const int* in_sizes, int n_in,
                              void* d_out, int out_size, void* d_ws, size_t ws_size,
                              hipStream_t stream) {
  (void)in_sizes; (void)n_in; (void)out_size; (void)ws_size;
  const float* pc = (const float*)d_in[0];
  const float* W[4][3];
  const float* Bb[4][3];
  for (int s = 0; s < 4; ++s)
    for (int l = 0; l < 3; ++l) {
      W[s][l] = (const float*)d_in[1 + s * 6 + l * 2];
      Bb[s][l] = (const float*)d_in[2 + s * 6 + l * 2];
    }

  // workspace layout (bytes): fidx 32KB | nidx 2MB | xyzA 96KB | xyzB 96KB |
  // featA 4MB | featB 4MB   (total ~10.2 MB)
  char* wsp = (char*)d_ws;
  int* fidx = (int*)wsp;
  int* nidx = (int*)(wsp + (32 << 10));
  float* xyzA = (float*)(wsp + (32 << 10) + (2 << 20));
  float* xyzB = xyzA + B_SZ * 2048 * 3;
  float* featA = xyzB + B_SZ * 2048 * 3;
  float* featB = featA + B_SZ * 2048 * 128;
  float* oxyz = (float*)d_out;           // [4,256,3]
  float* ofeat = oxyz + B_SZ * 256 * 3;  // [4,256,512]

  // ---------------- Stage 1: N=16384 -> S=2048, r=0.2, ns=64, 3->64->64->128
  hipLaunchKernelGGL((fps_kernel<16384, 2048, 512, false>), dim3(B_SZ), dim3(512), 0, stream,
                     pc, fidx);
  hipLaunchKernelGGL(gather_xyz_kernel, dim3(32, B_SZ), dim3(64), 0, stream,
                     pc, fidx, xyzA, 16384, 2048);
  hipLaunchKernelGGL((ball_query_kernel<16384, 64>), dim3(512, B_SZ), dim3(256), 0, stream,
                     pc, xyzA, nidx, 2048, (float)(0.2 * 0.2));
  hipLaunchKernelGGL((group_mlp_kernel<64, 1, 0, 64, 64, 128, 8, 32, 128>),
                     dim3(2048, B_SZ), dim3(256), 0, stream,
                     pc, xyzA, (const float*)nullptr, nidx,
                     W[0][0], Bb[0][0], W[0][1], Bb[0][1], W[0][2], Bb[0][2],
                     featA, 16384, 2048, 0.2f);

  // ---------------- Stage 2: N=2048 -> S=1024, r=0.4, ns=32, 131->128->128->256
  hipLaunchKernelGGL((fps_kernel<2048, 1024, 512, true>), dim3(B_SZ), dim3(512), 0, stream,
                     xyzA, fidx);
  hipLaunchKernelGGL(gather_xyz_kernel, dim3(16, B_SZ), dim3(64), 0, stream,
                     xyzA, fidx, xyzB, 2048, 1024);
  hipLaunchKernelGGL((ball_query_kernel<2048, 32>), dim3(256, B_SZ), dim3(256), 0, stream,
                     xyzA, xyzB, nidx, 1024, (float)(0.4 * 0.4));
  hipLaunchKernelGGL((group_mlp_kernel<32, 1, 128, 128, 128, 256, 4, 64, 256>),
                     dim3(1024, B_SZ), dim3(256), 0, stream,
                     xyzA, xyzB, featA, nidx,
                     W[1][0], Bb[1][0], W[1][1], Bb[1][1], W[1][2], Bb[1][2],
                     featB, 2048, 1024, 0.4f);

  // ---------------- Stage 3: N=1024 -> S=512, r=0.6, ns=16, 259->256->256->512
  hipLaunchKernelGGL((fps_kernel<1024, 512, 256, true>), dim3(B_SZ), dim3(256), 0, stream,
                     xyzB, fidx);
  hipLaunchKernelGGL(gather_xyz_kernel, dim3(8, B_SZ), dim3(64), 0, stream,
                     xyzB, fidx, xyzA, 1024, 512);
  hipLaunchKernelGGL((ball_query_kernel<1024, 16>), dim3(128, B_SZ), dim3(256), 0, stream,
                     xyzB, xyzA, nidx, 512, (float)(0.6 * 0.6));
  hipLaunchKernelGGL((group_mlp_kernel<16, 1, 256, 256, 256, 512, 2, 128, 512>),
                     dim3(512, B_SZ), dim3(256), 0, stream,
                     xyzB, xyzA, featB, nidx,
                     W[2][0], Bb[2][0], W[2][1], Bb[2][1], W[2][2], Bb[2][2],
                     featA, 1024, 512, 0.6f);

  // ---------------- Stage 4: N=512 -> S=256, r=1.2, ns=8, 515->512->512->512
  hipLaunchKernelGGL((fps_kernel<512, 256, 256, true>), dim3(B_SZ), dim3(256), 0, stream,
                     xyzA, fidx);
  hipLaunchKernelGGL(gather_xyz_kernel, dim3(4, B_SZ), dim3(64), 0, stream,
                     xyzA, fidx, oxyz, 512, 256);
  hipLaunchKernelGGL((ball_query_kernel<512, 8>), dim3(64, B_SZ), dim3(256), 0, stream,
                     xyzA, oxyz, nidx, 256, (float)(1.2 * 1.2));
  hipLaunchKernelGGL((group_mlp_kernel<8, 2, 512, 512, 512, 512, 2, 128, 516>),
                     dim3(128, B_SZ), dim3(256), 0, stream,
                     xyzA, oxyz, featA, nidx,
                     W[3][0], Bb[3][0], W[3][1], Bb[3][1], W[3][2], Bb[3][2],
                     ofeat, 512, 256, 1.2f);
}